// Round 1
// 322.292 us; speedup vs baseline: 1.0105x; 1.0105x over previous
//
#include <hip/hip_runtime.h>

// Problem constants (GlobalPointer: B=16, L=512, H=1024, HEADS=12, D=64)
#define BB 16
#define LL 512
#define HH 1024
#define HEADS 12
#define DD 64
#define N1 1536   // HEADS * 2 * DD
#define M1 8192   // BB * LL
#define NEGC 1e12f

typedef short bf16x8 __attribute__((ext_vector_type(8)));
typedef float f32x4 __attribute__((ext_vector_type(4)));

typedef const __attribute__((address_space(1))) void* as1cvp;
typedef __attribute__((address_space(3))) void* as3vp;

__device__ __forceinline__ unsigned short f2bf(float f) {
    union { float f; unsigned int u; } v; v.f = f;
    unsigned int u = v.u;
    return (unsigned short)((u + 0x7fffu + ((u >> 16) & 1u)) >> 16);
}

// async global -> LDS, 16B per lane; lds dest = wave-uniform base + lane*16
__device__ __forceinline__ void gl_lds16(const void* g, void* l) {
    __builtin_amdgcn_global_load_lds((as1cvp)g, (as3vp)l, 16, 0, 0);
}

// ---------------- Kernel 1: X fp32 -> bf16 (8192x1024) ----------------
__global__ __launch_bounds__(256) void k_conv_x(const float* __restrict__ X,
                                                unsigned short* __restrict__ Xb,
                                                int n4) {
    int i = blockIdx.x * 256 + threadIdx.x;
    if (i >= n4) return;
    float4 v = ((const float4*)X)[i];
    ushort4 o;
    o.x = f2bf(v.x); o.y = f2bf(v.y); o.z = f2bf(v.z); o.w = f2bf(v.w);
    ((ushort4*)Xb)[i] = o;
}

// ------------- Kernel 2: W (1024x1536 f32) -> Wt (1536x1024 bf16) -------------
__global__ __launch_bounds__(256) void k_trans_w(const float* __restrict__ W,
                                                 unsigned short* __restrict__ Wt) {
    __shared__ float tile[32][33];
    int n0 = blockIdx.x * 32;
    int k0 = blockIdx.y * 32;
    int tx = threadIdx.x;   // 0..31
    int ty = threadIdx.y;   // 0..7
#pragma unroll
    for (int i = 0; i < 4; i++) {
        int k = ty + i * 8;
        tile[k][tx] = W[(size_t)(k0 + k) * N1 + n0 + tx];
    }
    __syncthreads();
#pragma unroll
    for (int i = 0; i < 4; i++) {
        int n = ty + i * 8;
        Wt[(size_t)(n0 + n) * HH + k0 + tx] = f2bf(tile[tx][n]);
    }
}

// ------------- Kernel 3: C = Xb @ Wt^T (+bias, RoPE) -> Qr, Kr (bf16) -------------
// m97 structure: 128x128 tile, BK=32, 256 threads = 4 waves (2x2), each wave 64x64
// = 4x4 MFMA 16x16x32 tiles. Staging via global_load_lds width 16 (linear LDS).
// D layout: col=lane&15 (-> n), row=(lane>>4)*4+reg (-> m).
__global__ __launch_bounds__(256) void k_gemm1_rope(
    const unsigned short* __restrict__ Xb,   // [8192][1024]
    const unsigned short* __restrict__ Wt,   // [1536][1024]
    const float* __restrict__ bias,          // [1536]
    const float* __restrict__ pe,            // [512][64]  pe[l][2i]=sin, [2i+1]=cos
    unsigned short* __restrict__ Qr,         // [B*HEADS*512][64]
    unsigned short* __restrict__ Kr)
{
    __shared__ __align__(16) unsigned short As[128 * 32];  // 8 KB, linear [row][32]
    __shared__ __align__(16) unsigned short Bs[128 * 32];  // 8 KB
    int m0 = blockIdx.y * 128;
    int n0 = blockIdx.x * 128;
    int tid = threadIdx.x;
    int w  = tid >> 6;
    int ln = tid & 63;
    int lq = ln >> 4;
    int lm = ln & 15;
    int wm = (w & 1) * 64;
    int wn = (w >> 1) * 64;

    // staging: thread covers byte tid*16 (+4096 for second half) of the 8KB tile
    // -> global row = tid/4 (+64), k-col = (tid&3)*8
    int srow = tid >> 2;            // 0..63
    int scol = (tid & 3) * 8;       // 0,8,16,24
    const unsigned short* ga0 = &Xb[(size_t)(m0 + srow) * HH + scol];
    const unsigned short* ga1 = &Xb[(size_t)(m0 + 64 + srow) * HH + scol];
    const unsigned short* gb0 = &Wt[(size_t)(n0 + srow) * HH + scol];
    const unsigned short* gb1 = &Wt[(size_t)(n0 + 64 + srow) * HH + scol];
    unsigned short* la = &As[w * 512];          // wave-uniform base (w*1024 bytes)
    unsigned short* lb = &Bs[w * 512];

    f32x4 acc[4][4] = {};

    for (int kk = 0; kk < HH; kk += 32) {
        gl_lds16(ga0 + kk, la);
        gl_lds16(ga1 + kk, la + 2048);
        gl_lds16(gb0 + kk, lb);
        gl_lds16(gb1 + kk, lb + 2048);
        __syncthreads();   // drains vmcnt (global_load_lds) before ds_read

        bf16x8 a[4], b[4];
#pragma unroll
        for (int i = 0; i < 4; i++) {
            a[i] = *(const bf16x8*)&As[(wm + i * 16 + lm) * 32 + lq * 8];
            b[i] = *(const bf16x8*)&Bs[(wn + i * 16 + lm) * 32 + lq * 8];
        }
#pragma unroll
        for (int mi = 0; mi < 4; mi++)
#pragma unroll
            for (int ni = 0; ni < 4; ni++)
                acc[mi][ni] = __builtin_amdgcn_mfma_f32_16x16x32_bf16(
                    a[mi], b[ni], acc[mi][ni], 0, 0, 0);
        __syncthreads();   // frags consumed before next-tile overwrite
    }

    // Epilogue: bias + interleaved RoPE, scatter to Qr/Kr as bf16.
#pragma unroll
    for (int ni = 0; ni < 4; ni++) {
        int n = n0 + wn + ni * 16 + lm;         // 0..1535
        float bv = bias[n];
        int h = n >> 7;                          // head
        int c = n & 127;                         // channel in [0,128)
        int j = c & 63;                          // d-index
        int ii = j >> 1;                         // freq index
        bool isK = (c >= 64);
        unsigned short* dst = isK ? Kr : Qr;
#pragma unroll
        for (int mi = 0; mi < 4; mi++) {
#pragma unroll
            for (int r = 0; r < 4; r++) {
                int m = m0 + wm + mi * 16 + lq * 4 + r;   // 0..8191
                int l = m & (LL - 1);
                int bidx = m >> 9;
                float v = acc[mi][ni][r] + bv;
                float vp = __shfl_xor(v, 1, 64);          // partner n^1 == lane^1
                float2 sc = *(const float2*)&pe[l * 64 + 2 * ii]; // {sin, cos}
                float o = (j & 1) ? (v * sc.y + vp * sc.x) : (v * sc.y - vp * sc.x);
                size_t idx = ((size_t)(bidx * HEADS + h) * LL + l) * DD + j;
                dst[idx] = f2bf(o);
            }
        }
    }
}

// ------------- Kernel 4: logits = Q @ K^T, mask, /8 -------------
// Per (b,h): 512x512, K-dim 64. Block 64x64 tile, 4 waves (2x2), NO LDS
// (Q+K per bh = 128 KB, L1/L2-resident). Swapped MFMA: acc = mfma(Kfrag, Qfrag)
// -> D row (lq*4+r) = n, D col (lane&15) = m -> float4 stores along n.
__global__ __launch_bounds__(256) void k_gemm2(
    const unsigned short* __restrict__ Qr,
    const unsigned short* __restrict__ Kr,
    const int* __restrict__ mask,            // [B][L]
    float* __restrict__ out)                 // [B][HEADS][L][L]
{
    int bh = blockIdx.z;
    int b  = bh / HEADS;
    int n0 = blockIdx.x * 64;
    int m0 = blockIdx.y * 64;
    int tid = threadIdx.x;
    int w  = tid >> 6;
    int ln = tid & 63;
    int lq = ln >> 4;
    int lm = ln & 15;
    int mw = (w & 1) * 32;
    int nw = (w >> 1) * 32;

    const unsigned short* Qb = Qr + (size_t)bh * LL * DD;
    const unsigned short* Kb = Kr + (size_t)bh * LL * DD;

    f32x4 acc[2][2] = {};   // [nt][mt]
#pragma unroll
    for (int kk = 0; kk < 64; kk += 32) {
        bf16x8 q0 = *(const bf16x8*)&Qb[(size_t)(m0 + mw + lm) * DD + kk + lq * 8];
        bf16x8 q1 = *(const bf16x8*)&Qb[(size_t)(m0 + mw + 16 + lm) * DD + kk + lq * 8];
        bf16x8 k0 = *(const bf16x8*)&Kb[(size_t)(n0 + nw + lm) * DD + kk + lq * 8];
        bf16x8 k1 = *(const bf16x8*)&Kb[(size_t)(n0 + nw + 16 + lm) * DD + kk + lq * 8];
        acc[0][0] = __builtin_amdgcn_mfma_f32_16x16x32_bf16(k0, q0, acc[0][0], 0, 0, 0);
        acc[0][1] = __builtin_amdgcn_mfma_f32_16x16x32_bf16(k0, q1, acc[0][1], 0, 0, 0);
        acc[1][0] = __builtin_amdgcn_mfma_f32_16x16x32_bf16(k1, q0, acc[1][0], 0, 0, 0);
        acc[1][1] = __builtin_amdgcn_mfma_f32_16x16x32_bf16(k1, q1, acc[1][1], 0, 0, 0);
    }

#pragma unroll
    for (int nt = 0; nt < 2; nt++) {
        int nb = n0 + nw + nt * 16 + lq * 4;            // 4 consecutive n in regs
        int4 mv = *(const int4*)&mask[b * LL + nb];     // 16B-aligned
#pragma unroll
        for (int mt = 0; mt < 2; mt++) {
            int m = m0 + mw + mt * 16 + lm;
            f32x4 o;
#pragma unroll
            for (int r = 0; r < 4; r++) {
                int n = nb + r;
                float pm = (float)(((const int*)&mv)[r]);
                float dot = acc[nt][mt][r];
                float val = (dot * pm - (1.0f - pm) * NEGC - (n < m ? NEGC : 0.0f)) * 0.125f;
                o[r] = val;
            }
            __builtin_nontemporal_store(o, (f32x4*)&out[((size_t)bh * LL + m) * LL + nb]);
        }
    }
}

extern "C" void kernel_launch(void* const* d_in, const int* in_sizes, int n_in,
                              void* d_out, int out_size, void* d_ws, size_t ws_size,
                              hipStream_t stream) {
    const float* X    = (const float*)d_in[0];   // (16,512,1024)
    const int*   mask = (const int*)d_in[1];     // (16,512)
    const float* W    = (const float*)d_in[2];   // (1024,1536)
    const float* bias = (const float*)d_in[3];   // (1536,)
    const float* pe   = (const float*)d_in[4];   // (512,64)
    float* out = (float*)d_out;

    char* ws = (char*)d_ws;
    unsigned short* Xb = (unsigned short*)ws;                                // 16.78 MB
    unsigned short* Wt = (unsigned short*)(ws + 16777216);                   // 3.15 MB
    unsigned short* Qr = (unsigned short*)(ws + 16777216 + 3145728);         // 12.58 MB
    unsigned short* Kr = Qr + (size_t)BB * HEADS * LL * DD;                  // 12.58 MB

    // 1) convert X to bf16
    k_conv_x<<<dim3((M1 * HH / 4 + 255) / 256), dim3(256), 0, stream>>>(X, Xb, M1 * HH / 4);
    // 2) transpose+convert W
    k_trans_w<<<dim3(N1 / 32, HH / 32), dim3(32, 8), 0, stream>>>(W, Wt);
    // 3) GEMM1 + bias + RoPE -> Qr, Kr  (128x128 tiles, global_load_lds staging)
    k_gemm1_rope<<<dim3(N1 / 128, M1 / 128), dim3(256), 0, stream>>>(Xb, Wt, bias, pe, Qr, Kr);
    // 4) GEMM2 + mask + scale -> out  (no-LDS, swapped MFMA, float4 NT stores)
    k_gemm2<<<dim3(LL / 64, LL / 64, BB * HEADS), dim3(256), 0, stream>>>(Qr, Kr, mask, out);
}